// Round 15
// baseline (126.100 us; speedup 1.0000x reference)
//
#include <hip/hip_runtime.h>
#include <math.h>

#define TWO_PI_F 6.28318530717958647692f
#define BN_EPS_F 1e-5f
#define NB1 2048  // k1 blocks (scan): 1 row/thread exactly at B=524288
#define NT 256

// ---------------------------------------------------------------------------
// Workspace layout (float offsets on d_ws). All cross-kernel data is written
// with plain stores in kernel N and read in kernel N+1 (kernel boundary
// coherence). No atomics, no zero-init required.
//   [BMIN_OFF..+2048) : per-block min   (k1 -> k2)
//   [BMAX_OFF..+2048) : per-block max   (k1 -> k2)
//   [TAB_OFF..+576)   : UrT[16][16] | UiT[16][16] | AT[16][4]  (k1 internal)
//   [CQ_OFF..+400)    : C[p][q][j] quadratic-form table        (k1 -> k2)
//   [SSLOT_OFF..+16k) : per-block BN stats [blk][8]            (k2 -> k3)
// ---------------------------------------------------------------------------
#define BMIN_OFF 256
#define BMAX_OFF 2304
#define TAB_OFF 4352
#define CQ_OFF 4928
#define SSLOT_OFF 5376

// ===========================================================================
// K1: min/max over x[:,0:4], 1 row/thread -> per-block slots; block 0 also
// builds the circuit tables AND the folded quadratic-form table C:
//   o_j = sum_{p,q} C_j[p][q] * P01[p] * P23[q]
// (P01/P23 = 10 symmetric pair-products; C from U and A^T, verified R12/R14).
// ===========================================================================
__global__ __launch_bounds__(NT) void k1_scan_tab(const float* __restrict__ x,
                                                  const float* __restrict__ w,
                                                  const float* __restrict__ fc_w,
                                                  float* __restrict__ wsf, int B) {
  int r = blockIdx.x * NT + threadIdx.x;
  float fmn = __builtin_inff(), fmx = -__builtin_inff();
  if (r < B) {
    float4 v = *(const float4*)(x + (size_t)r * 16);
    fmn = fminf(fminf(v.x, v.y), fminf(v.z, v.w));
    fmx = fmaxf(fmaxf(v.x, v.y), fmaxf(v.z, v.w));
  }
#pragma unroll
  for (int d = 32; d; d >>= 1) {
    fmn = fminf(fmn, __shfl_down(fmn, d));
    fmx = fmaxf(fmx, __shfl_down(fmx, d));
  }
  __shared__ float smn[4], smx[4];
  int wv = threadIdx.x >> 6, ln = threadIdx.x & 63;
  if (ln == 0) { smn[wv] = fmn; smx[wv] = fmx; }
  __syncthreads();
  if (threadIdx.x == 0) {
    wsf[BMIN_OFF + blockIdx.x] =
        fminf(fminf(smn[0], smn[1]), fminf(smn[2], smn[3]));
    wsf[BMAX_OFF + blockIdx.x] =
        fmaxf(fmaxf(smx[0], smx[1]), fmaxf(smx[2], smx[3]));
  }

  if (blockIdx.x == 0) {
    int tid = threadIdx.x;
    if (tid < 16) {
      // Column tid of the fixed 3-layer RY/RZ/CNOT unitary; store transposed.
      float sr[16], si[16];
#pragma unroll
      for (int k = 0; k < 16; ++k) { sr[k] = (k == tid) ? 1.f : 0.f; si[k] = 0.f; }
#pragma unroll
      for (int l = 0; l < 3; ++l) {
#pragma unroll
        for (int i = 0; i < 4; ++i) {
          const int m = 8 >> i;
          float ryc, rys, rzc, rzs;
          __sincosf(0.5f * w[(l * 4 + i) * 2 + 0], &rys, &ryc);
          __sincosf(0.5f * w[(l * 4 + i) * 2 + 1], &rzs, &rzc);
#pragma unroll
          for (int k = 0; k < 16; ++k) {
            if (!(k & m)) {
              int k1 = k | m;
              float a0r = sr[k], a0i = si[k], a1r = sr[k1], a1i = si[k1];
              sr[k] = ryc * a0r - rys * a1r;
              si[k] = ryc * a0i - rys * a1i;
              sr[k1] = rys * a0r + ryc * a1r;
              si[k1] = rys * a0i + ryc * a1i;
            }
          }
#pragma unroll
          for (int k = 0; k < 16; ++k) {
            float ps = (k & m) ? rzs : -rzs;
            float rr = sr[k], ii = si[k];
            sr[k] = rr * rzc - ii * ps;
            si[k] = rr * ps + ii * rzc;
          }
        }
#pragma unroll
        for (int c = 0; c < 4; ++c) {
          const int mc = 8 >> c;
          const int mt = 8 >> ((c + 1) & 3);
#pragma unroll
          for (int k = 0; k < 16; ++k) {
            if ((k & mc) && !(k & mt)) {
              int k2 = k | mt;
              float tt;
              tt = sr[k]; sr[k] = sr[k2]; sr[k2] = tt;
              tt = si[k]; si[k] = si[k2]; si[k2] = tt;
            }
          }
        }
      }
#pragma unroll
      for (int k = 0; k < 16; ++k) {
        wsf[TAB_OFF + tid * 16 + k] = sr[k];
        wsf[TAB_OFF + 256 + tid * 16 + k] = si[k];
      }
    } else if (tid == 16) {
      // AT[k][j] = sum_i fc_w[j][i] * Zparity(k,i)
      for (int k = 0; k < 16; ++k)
        for (int j = 0; j < 4; ++j) {
          float s = 0.f;
          for (int i = 0; i < 4; ++i)
            s += fc_w[j * 4 + i] * ((k & (8 >> i)) ? -1.f : 1.f);
          wsf[TAB_OFF + 512 + k * 4 + j] = s;
        }
    }
  }

  // Build C from the tables (same block: visible after barrier).
  __syncthreads();
  if (blockIdx.x == 0 && threadIdx.x < 100) {
    const int tid = threadIdx.x;
    const int p = tid / 10, q = tid % 10;
    // canonical pair list: 0:(0,0) 1:(0,1) 2:(0,2) 3:(0,3) 4:(1,1)
    //                      5:(1,2) 6:(1,3) 7:(2,2) 8:(2,3) 9:(3,3)
    int pu, pv, qu, qv;
    if (p < 4) { pu = 0; pv = p; }
    else if (p < 7) { pu = 1; pv = p - 3; }
    else if (p < 9) { pu = 2; pv = p - 5; }
    else { pu = 3; pv = 3; }
    if (q < 4) { qu = 0; qv = q; }
    else if (q < 7) { qu = 1; qv = q - 3; }
    else if (q < 9) { qu = 2; qv = q - 5; }
    else { qu = 3; qv = 3; }
    const float* __restrict__ Tr = wsf + TAB_OFF;
    const float* __restrict__ Ti = wsf + TAB_OFF + 256;
    const float* __restrict__ At = wsf + TAB_OFF + 512;
    const int nh = (pu == pv) ? 1 : 2;
    const int nl = (qu == qv) ? 1 : 2;
    float c[4] = {0.f, 0.f, 0.f, 0.f};
    for (int hh = 0; hh < nh; ++hh) {
      int ha = hh ? pv : pu, hb = hh ? pu : pv;
      for (int ll = 0; ll < nl; ++ll) {
        int la = ll ? qv : qu, lb = ll ? qu : qv;
        int a = 4 * ha + la, b = 4 * hb + lb;
        for (int k = 0; k < 16; ++k) {
          float rr = Tr[a * 16 + k] * Tr[b * 16 + k] +
                     Ti[a * 16 + k] * Ti[b * 16 + k];
#pragma unroll
          for (int j = 0; j < 4; ++j) c[j] = fmaf(At[k * 4 + j], rr, c[j]);
        }
      }
    }
#pragma unroll
    for (int j = 0; j < 4; ++j) wsf[CQ_OFF + tid * 4 + j] = c[j];
  }
}

// ===========================================================================
// K2: 1 sample/thread, 8 blocks/CU. R14 lesson: k2 is STALL-bound on the
// per-thread table loads, not VALU-bound. Fix: stage Cq (1.6 KB) into LDS
// once per block (waves 2-3, overlapping wave 0's min/max slot reduce);
// hot loop reads lcq4[t] -- same-address LDS b128 = broadcast, conflict-free,
// latency hidden at 8 waves/SIMD. Zero global loads in the hot loop.
// ===========================================================================
__global__ __launch_bounds__(NT, 8) void k2_main(const float* __restrict__ x,
                                                 const float* __restrict__ wsf,
                                                 float* __restrict__ sslot,
                                                 float* __restrict__ out, int B) {
  const int tid = threadIdx.x;
  const int s0 = blockIdx.x * NT + tid;
  const int wv = tid >> 6, ln = tid & 63;
  __shared__ float4 lcq4[100];  // Cq staged: lcq4[t] = C[t][0..3]
  __shared__ float sbc[2];
  __shared__ float red[4][8];

  const bool h0 = s0 < B;
  float4 xa = h0 ? *(const float4*)(x + (size_t)s0 * 16) : make_float4(0, 0, 0, 0);

  // waves 2-3: stage Cq into LDS (overlaps wave 0's min/max reduce below)
  if (tid >= 128 && tid < 228) {
    int t = tid - 128;
    lcq4[t] = *(const float4*)(wsf + CQ_OFF + t * 4);  // 16B-aligned
  }
  // wave 0: global min/max from the 2048 k1 slots
  if (wv == 0) {
    float gm = __builtin_inff(), gM = -__builtin_inff();
#pragma unroll
    for (int q = 0; q < NB1 / 64; ++q) {
      gm = fminf(gm, wsf[BMIN_OFF + ln + q * 64]);
      gM = fmaxf(gM, wsf[BMAX_OFF + ln + q * 64]);
    }
#pragma unroll
    for (int d = 32; d; d >>= 1) {
      gm = fminf(gm, __shfl_down(gm, d));
      gM = fmaxf(gM, __shfl_down(gM, d));
    }
    if (ln == 0) { sbc[0] = gm; sbc[1] = gM; }
  }
  __syncthreads();
  const float gm = sbc[0];
  const float ssc = TWO_PI_F * 0.5f / (sbc[1] - gm + 1e-8f);  // half-angle

  float cc[4], sn[4];
  {
    float a[4] = {xa.x, xa.y, xa.z, xa.w};
#pragma unroll
    for (int i = 0; i < 4; ++i) __sincosf((a[i] - gm) * ssc, &sn[i], &cc[i]);
  }
  float A01[4] = {cc[0] * cc[1], cc[0] * sn[1], sn[0] * cc[1], sn[0] * sn[1]};
  float A23[4] = {cc[2] * cc[3], cc[2] * sn[3], sn[2] * cc[3], sn[2] * sn[3]};
  float P01[10], P23[10];
  P01[0] = A01[0] * A01[0]; P01[1] = A01[0] * A01[1]; P01[2] = A01[0] * A01[2];
  P01[3] = A01[0] * A01[3]; P01[4] = A01[1] * A01[1]; P01[5] = A01[1] * A01[2];
  P01[6] = A01[1] * A01[3]; P01[7] = A01[2] * A01[2]; P01[8] = A01[2] * A01[3];
  P01[9] = A01[3] * A01[3];
  P23[0] = A23[0] * A23[0]; P23[1] = A23[0] * A23[1]; P23[2] = A23[0] * A23[2];
  P23[3] = A23[0] * A23[3]; P23[4] = A23[1] * A23[1]; P23[5] = A23[1] * A23[2];
  P23[6] = A23[1] * A23[3]; P23[7] = A23[2] * A23[2]; P23[8] = A23[2] * A23[3];
  P23[9] = A23[3] * A23[3];

  float o[4] = {0.f, 0.f, 0.f, 0.f};
#pragma unroll
  for (int t = 0; t < 100; ++t) {  // t/10, t%10 fold to constants on unroll
    float4 c4 = lcq4[t];           // LDS broadcast (same addr, all lanes)
    float vv = P01[t / 10] * P23[t % 10];
    o[0] = fmaf(c4.x, vv, o[0]);
    o[1] = fmaf(c4.y, vv, o[1]);
    o[2] = fmaf(c4.z, vv, o[2]);
    o[3] = fmaf(c4.w, vv, o[3]);
  }

  if (h0)
    *(float4*)(out + (size_t)s0 * 4) = make_float4(o[0], o[1], o[2], o[3]);

  // per-block BN stat partials
  float vals[8];
#pragma unroll
  for (int j = 0; j < 4; ++j) {
    float v = h0 ? o[j] : 0.f;
    vals[j] = v;
    vals[4 + j] = v * v;
  }
#pragma unroll
  for (int j = 0; j < 8; ++j) {
#pragma unroll
    for (int d = 32; d; d >>= 1) vals[j] += __shfl_down(vals[j], d);
  }
  if (ln == 0) {
#pragma unroll
    for (int j = 0; j < 8; ++j) red[wv][j] = vals[j];
  }
  __syncthreads();
  if (tid < 8) {
    sslot[blockIdx.x * 8 + tid] =
        red[0][tid] + red[1][tid] + red[2][tid] + red[3][tid];
  }
}

// ===========================================================================
// K3: ALL-256-THREAD stat reduce with 4-way ILP (R12 lesson: wave-0-only
// serial chain = 68 us). Stride NT*4 === 0 mod 8 preserves the j = tid&7
// element mapping; then lanes {ln, ln+8..ln+56} combine via shfl_down,
// waves combine via LDS. Then BN finalize in-place (2 float4s/thread).
// ===========================================================================
__global__ __launch_bounds__(NT) void k3_final(float* __restrict__ out,
                                               const float* __restrict__ sslot,
                                               const float* __restrict__ gamma,
                                               const float* __restrict__ beta,
                                               int B, int nb2) {
  const int tid = threadIdx.x;
  const int gtid = blockIdx.x * NT + tid;
  const int H = gridDim.x * NT;
  const int wv = tid >> 6, ln = tid & 63;
  __shared__ float red[4][8];
  __shared__ float sst[8];

  const int n = nb2 * 8;
  float v0 = 0.f, v1 = 0.f, v2 = 0.f, v3 = 0.f;
  for (int e = tid; e < n; e += NT * 4) {
    v0 += sslot[e];
    if (e + NT < n) v1 += sslot[e + NT];
    if (e + 2 * NT < n) v2 += sslot[e + 2 * NT];
    if (e + 3 * NT < n) v3 += sslot[e + 3 * NT];
  }
  float v = (v0 + v1) + (v2 + v3);  // belongs to j = tid & 7
  v += __shfl_down(v, 8);
  v += __shfl_down(v, 16);
  v += __shfl_down(v, 32);
  if (ln < 8) red[wv][ln] = v;
  __syncthreads();
  if (tid < 8)
    sst[tid] = red[0][tid] + red[1][tid] + red[2][tid] + red[3][tid];
  __syncthreads();

  const float inv = 1.0f / (float)B;
  float sc[4], sh[4];
#pragma unroll
  for (int j = 0; j < 4; ++j) {
    float mean = sst[j] * inv;
    float var = sst[4 + j] * inv - mean * mean;
    float is = rsqrtf(var + BN_EPS_F);
    sc[j] = gamma[j] * is;
    sh[j] = beta[j] - mean * sc[j];
  }
#pragma unroll
  for (int p = 0; p < 2; ++p) {
    int s = gtid + p * H;
    if (s < B) {
      float4 q = *(float4*)(out + (size_t)s * 4);
      *(float4*)(out + (size_t)s * 4) =
          make_float4(fmaf(q.x, sc[0], sh[0]), fmaf(q.y, sc[1], sh[1]),
                      fmaf(q.z, sc[2], sh[2]), fmaf(q.w, sc[3], sh[3]));
    }
  }
}

extern "C" void kernel_launch(void* const* d_in, const int* in_sizes, int n_in,
                              void* d_out, int out_size, void* d_ws, size_t ws_size,
                              hipStream_t stream) {
  const float* x = (const float*)d_in[0];
  const float* w = (const float*)d_in[1];
  const float* fc_w = (const float*)d_in[2];
  const float* gamma = (const float*)d_in[4];
  const float* beta = (const float*)d_in[5];
  float* out = (float*)d_out;
  float* wsf = (float*)d_ws;
  int B = in_sizes[0] / 16;

  int nb2 = (B + NT - 1) / NT;            // k2: 1 sample/thread
  int nb3 = (B + 2 * NT - 1) / (2 * NT);  // k3: 2 samples/thread

  k1_scan_tab<<<NB1, NT, 0, stream>>>(x, w, fc_w, wsf, B);
  k2_main<<<nb2, NT, 0, stream>>>(x, wsf, wsf + SSLOT_OFF, out, B);
  k3_final<<<nb3, NT, 0, stream>>>(out, wsf + SSLOT_OFF, gamma, beta, B, nb2);
}

// Round 16
// 113.600 us; speedup vs baseline: 1.1100x; 1.1100x over previous
//
#include <hip/hip_runtime.h>
#include <math.h>

#define TWO_PI_F 6.28318530717958647692f
#define BN_EPS_F 1e-5f
#define NB1 2048  // k1 blocks (scan): 1 row/thread exactly at B=524288
#define NB2 1024  // k2/k3 blocks
#define NT 256

// ---------------------------------------------------------------------------
// Workspace layout (float offsets on d_ws). All cross-kernel data is written
// with plain stores in kernel N and read in kernel N+1 (runtime handles
// inter-kernel coherence). No atomics, no zero-init required.
//   [BMIN_OFF..+2048) : per-block min   (k1 -> k2)
//   [BMAX_OFF..+2048) : per-block max   (k1 -> k2)
//   [TAB_OFF..+576)   : UrT[16][16] | UiT[16][16] | AT[16][4]  (k1 -> k2)
//   [SSLOT_OFF..+8192): per-block BN stats [blk][8] = sum0..3,ssq0..3 (k2 -> k3)
// ---------------------------------------------------------------------------
#define BMIN_OFF 256
#define BMAX_OFF 2304
#define TAB_OFF 4352
#define SSLOT_OFF 4992

// ===========================================================================
// K1: min/max over x[:,0:4], 1 row/thread -> per-block slots; block 0 also
// builds the fixed circuit tables (U = weight-layer unitary, A = parity@fc_w).
// ===========================================================================
__global__ __launch_bounds__(NT) void k1_scan_tab(const float* __restrict__ x,
                                                  const float* __restrict__ w,
                                                  const float* __restrict__ fc_w,
                                                  float* __restrict__ wsf, int B) {
  int r = blockIdx.x * NT + threadIdx.x;
  float fmn = __builtin_inff(), fmx = -__builtin_inff();
  if (r < B) {
    float4 v = *(const float4*)(x + (size_t)r * 16);
    fmn = fminf(fminf(v.x, v.y), fminf(v.z, v.w));
    fmx = fmaxf(fmaxf(v.x, v.y), fmaxf(v.z, v.w));
  }
#pragma unroll
  for (int d = 32; d; d >>= 1) {
    fmn = fminf(fmn, __shfl_down(fmn, d));
    fmx = fmaxf(fmx, __shfl_down(fmx, d));
  }
  __shared__ float smn[4], smx[4];
  int wv = threadIdx.x >> 6, ln = threadIdx.x & 63;
  if (ln == 0) { smn[wv] = fmn; smx[wv] = fmx; }
  __syncthreads();
  if (threadIdx.x == 0) {
    wsf[BMIN_OFF + blockIdx.x] =
        fminf(fminf(smn[0], smn[1]), fminf(smn[2], smn[3]));
    wsf[BMAX_OFF + blockIdx.x] =
        fmaxf(fmaxf(smx[0], smx[1]), fmaxf(smx[2], smx[3]));
  }

  if (blockIdx.x == 0) {
    int tid = threadIdx.x;
    if (tid < 16) {
      // Column tid of the fixed 3-layer RY/RZ/CNOT unitary; store transposed.
      float sr[16], si[16];
#pragma unroll
      for (int k = 0; k < 16; ++k) { sr[k] = (k == tid) ? 1.f : 0.f; si[k] = 0.f; }
#pragma unroll
      for (int l = 0; l < 3; ++l) {
#pragma unroll
        for (int i = 0; i < 4; ++i) {
          const int m = 8 >> i;
          float ryc, rys, rzc, rzs;
          __sincosf(0.5f * w[(l * 4 + i) * 2 + 0], &rys, &ryc);
          __sincosf(0.5f * w[(l * 4 + i) * 2 + 1], &rzs, &rzc);
#pragma unroll
          for (int k = 0; k < 16; ++k) {
            if (!(k & m)) {
              int k1 = k | m;
              float a0r = sr[k], a0i = si[k], a1r = sr[k1], a1i = si[k1];
              sr[k] = ryc * a0r - rys * a1r;
              si[k] = ryc * a0i - rys * a1i;
              sr[k1] = rys * a0r + ryc * a1r;
              si[k1] = rys * a0i + ryc * a1i;
            }
          }
#pragma unroll
          for (int k = 0; k < 16; ++k) {
            float ps = (k & m) ? rzs : -rzs;
            float rr = sr[k], ii = si[k];
            sr[k] = rr * rzc - ii * ps;
            si[k] = rr * ps + ii * rzc;
          }
        }
#pragma unroll
        for (int c = 0; c < 4; ++c) {
          const int mc = 8 >> c;
          const int mt = 8 >> ((c + 1) & 3);
#pragma unroll
          for (int k = 0; k < 16; ++k) {
            if ((k & mc) && !(k & mt)) {
              int k2 = k | mt;
              float tt;
              tt = sr[k]; sr[k] = sr[k2]; sr[k2] = tt;
              tt = si[k]; si[k] = si[k2]; si[k2] = tt;
            }
          }
        }
      }
#pragma unroll
      for (int k = 0; k < 16; ++k) {
        wsf[TAB_OFF + tid * 16 + k] = sr[k];
        wsf[TAB_OFF + 256 + tid * 16 + k] = si[k];
      }
    } else if (tid == 16) {
      // AT[k][j] = sum_i fc_w[j][i] * Zparity(k,i)
      for (int k = 0; k < 16; ++k)
        for (int j = 0; j < 4; ++j) {
          float s = 0.f;
          for (int i = 0; i < 4; ++i)
            s += fc_w[j * 4 + i] * ((k & (8 >> i)) ? -1.f : 1.f);
          wsf[TAB_OFF + 512 + k * 4 + j] = s;
        }
    }
  }
}

// Two-sample fused circuit+linear: o = A|U v|^2 (no bias; constant bias
// cancels exactly in BatchNorm). tab -> wave-uniform scalar loads.
__device__ __forceinline__ void qfc_pair(const float* __restrict__ tab,
                                         const float* c0, const float* s0,
                                         const float* c1, const float* s1,
                                         float* o0, float* o1) {
  const float* __restrict__ Ur = tab;
  const float* __restrict__ Ui = tab + 256;
  const float* __restrict__ At = tab + 512;
  float A01_0[4] = {c0[0] * c0[1], c0[0] * s0[1], s0[0] * c0[1], s0[0] * s0[1]};
  float A23_0[4] = {c0[2] * c0[3], c0[2] * s0[3], s0[2] * c0[3], s0[2] * s0[3]};
  float A01_1[4] = {c1[0] * c1[1], c1[0] * s1[1], s1[0] * c1[1], s1[0] * s1[1]};
  float A23_1[4] = {c1[2] * c1[3], c1[2] * s1[3], s1[2] * c1[3], s1[2] * s1[3]};
  float yr0[16], yi0[16], yr1[16], yi1[16];
#pragma unroll
  for (int k = 0; k < 16; ++k) { yr0[k] = yi0[k] = yr1[k] = yi1[k] = 0.f; }
#pragma unroll
  for (int a = 0; a < 16; ++a) {
    float va0 = A01_0[a >> 2] * A23_0[a & 3];
    float va1 = A01_1[a >> 2] * A23_1[a & 3];
#pragma unroll
    for (int k = 0; k < 16; ++k) {
      float ur = Ur[a * 16 + k], ui = Ui[a * 16 + k];
      yr0[k] = fmaf(ur, va0, yr0[k]);
      yi0[k] = fmaf(ui, va0, yi0[k]);
      yr1[k] = fmaf(ur, va1, yr1[k]);
      yi1[k] = fmaf(ui, va1, yi1[k]);
    }
  }
#pragma unroll
  for (int j = 0; j < 4; ++j) { o0[j] = 0.f; o1[j] = 0.f; }
#pragma unroll
  for (int k = 0; k < 16; ++k) {
    float p0 = fmaf(yr0[k], yr0[k], yi0[k] * yi0[k]);
    float p1 = fmaf(yr1[k], yr1[k], yi1[k] * yi1[k]);
#pragma unroll
    for (int j = 0; j < 4; ++j) {
      float av = At[k * 4 + j];
      o0[j] = fmaf(av, p0, o0[j]);
      o1[j] = fmaf(av, p1, o1[j]);
    }
  }
}

// ===========================================================================
// K2: reduce min/max slots per-wave; 2 samples/thread circuit+linear; write
// pre-BN out; per-block BN stat partials -> plain-store slots [blk][8].
// ===========================================================================
__global__ __launch_bounds__(NT) void k2_main(const float* __restrict__ x,
                                              const float* __restrict__ wsf,
                                              float* __restrict__ sslot,
                                              float* __restrict__ out, int B) {
  const int tid = threadIdx.x;
  const int gtid = blockIdx.x * NT + tid;
  const int H = NB2 * NT;  // 262144
  const int wv = tid >> 6, ln = tid & 63;
  const float* __restrict__ tab = wsf + TAB_OFF;

  // global min/max from the 2048 k1 slots (redundant per-wave reduce)
  float gm = __builtin_inff(), gM = -__builtin_inff();
#pragma unroll
  for (int q = 0; q < NB1 / 64; ++q) {
    int i = ln + q * 64;
    gm = fminf(gm, wsf[BMIN_OFF + i]);
    gM = fmaxf(gM, wsf[BMAX_OFF + i]);
  }
#pragma unroll
  for (int d = 32; d; d >>= 1) {
    gm = fminf(gm, __shfl_down(gm, d));
    gM = fmaxf(gM, __shfl_down(gM, d));
  }
  gm = __shfl(gm, 0);
  gM = __shfl(gM, 0);
  const float ssc = TWO_PI_F * 0.5f / (gM - gm + 1e-8f);  // half-angle scale

  const int s0 = gtid, s1 = gtid + H;
  const bool h0 = s0 < B, h1 = s1 < B;
  float4 xa = h0 ? *(const float4*)(x + (size_t)s0 * 16) : make_float4(0, 0, 0, 0);
  float4 xb = h1 ? *(const float4*)(x + (size_t)s1 * 16) : make_float4(0, 0, 0, 0);

  float a0[4] = {xa.x, xa.y, xa.z, xa.w};
  float a1[4] = {xb.x, xb.y, xb.z, xb.w};
  float c0[4], sn0[4], c1[4], sn1[4];
#pragma unroll
  for (int i = 0; i < 4; ++i) {
    __sincosf((a0[i] - gm) * ssc, &sn0[i], &c0[i]);
    __sincosf((a1[i] - gm) * ssc, &sn1[i], &c1[i]);
  }
  float o0[4], o1[4];
  qfc_pair(tab, c0, sn0, c1, sn1, o0, o1);

  if (h0)
    *(float4*)(out + (size_t)s0 * 4) = make_float4(o0[0], o0[1], o0[2], o0[3]);
  if (h1)
    *(float4*)(out + (size_t)s1 * 4) = make_float4(o1[0], o1[1], o1[2], o1[3]);

  // per-block BN stat partials
  float vals[8];
#pragma unroll
  for (int j = 0; j < 4; ++j) {
    float v0 = h0 ? o0[j] : 0.f, v1 = h1 ? o1[j] : 0.f;
    vals[j] = v0 + v1;
    vals[4 + j] = fmaf(v0, v0, v1 * v1);
  }
#pragma unroll
  for (int j = 0; j < 8; ++j) {
#pragma unroll
    for (int d = 32; d; d >>= 1) vals[j] += __shfl_down(vals[j], d);
  }
  __shared__ float red[4][8];
  if (ln == 0) {
#pragma unroll
    for (int j = 0; j < 8; ++j) red[wv][j] = vals[j];
  }
  __syncthreads();
  if (tid < 8) {
    sslot[blockIdx.x * 8 + tid] =
        red[0][tid] + red[1][tid] + red[2][tid] + red[3][tid];
  }
}

// ===========================================================================
// K3: per-wave reduce of the 1024x8 stat slots (coalesced 64-float rows),
// then BN finalize in-place on out (2 float4s/thread).
// ===========================================================================
__global__ __launch_bounds__(NT) void k3_final(float* __restrict__ out,
                                               const float* __restrict__ sslot,
                                               const float* __restrict__ gamma,
                                               const float* __restrict__ beta,
                                               int B) {
  const int tid = threadIdx.x;
  const int gtid = blockIdx.x * NT + tid;
  const int H = NB2 * NT;
  const int ln = tid & 63;

  // flat element e = blk*8 + j; lane ln sums e ≡ ln (mod 64) -> j = ln&7
  float v = 0.f;
#pragma unroll
  for (int k = 0; k < (NB2 * 8) / 64; ++k) v += sslot[k * 64 + ln];
#pragma unroll
  for (int d = 32; d >= 8; d >>= 1) v += __shfl_down(v, d);
  // lanes 0..7 hold totals for j=0..7; broadcast all 8 to every lane
  float st[8];
#pragma unroll
  for (int j = 0; j < 8; ++j) st[j] = __shfl(v, j);

  const float inv = 1.0f / (float)B;
  float sc[4], sh[4];
#pragma unroll
  for (int j = 0; j < 4; ++j) {
    float mean = st[j] * inv;
    float var = st[4 + j] * inv - mean * mean;
    float is = rsqrtf(var + BN_EPS_F);
    sc[j] = gamma[j] * is;
    sh[j] = beta[j] - mean * sc[j];
  }
#pragma unroll
  for (int p = 0; p < 2; ++p) {
    int s = gtid + p * H;
    if (s < B) {
      float4 q = *(float4*)(out + (size_t)s * 4);
      *(float4*)(out + (size_t)s * 4) =
          make_float4(fmaf(q.x, sc[0], sh[0]), fmaf(q.y, sc[1], sh[1]),
                      fmaf(q.z, sc[2], sh[2]), fmaf(q.w, sc[3], sh[3]));
    }
  }
}

extern "C" void kernel_launch(void* const* d_in, const int* in_sizes, int n_in,
                              void* d_out, int out_size, void* d_ws, size_t ws_size,
                              hipStream_t stream) {
  const float* x = (const float*)d_in[0];
  const float* w = (const float*)d_in[1];
  const float* fc_w = (const float*)d_in[2];
  const float* gamma = (const float*)d_in[4];
  const float* beta = (const float*)d_in[5];
  float* out = (float*)d_out;
  float* wsf = (float*)d_ws;
  int B = in_sizes[0] / 16;

  k1_scan_tab<<<NB1, NT, 0, stream>>>(x, w, fc_w, wsf, B);
  k2_main<<<NB2, NT, 0, stream>>>(x, wsf, wsf + SSLOT_OFF, out, B);
  k3_final<<<NB2, NT, 0, stream>>>(out, wsf + SSLOT_OFF, gamma, beta, B);
}